// Round 7
// baseline (1403.705 us; speedup 1.0000x reference)
//
#include <hip/hip_runtime.h>
#include <cstdint>
#include <cstddef>

// ---------------------------------------------------------------------------
// ParameterizedKnowledgeStore: out = softmax(q @ (bank@Wk+bk)^T) @ (bank@Wv+bv)
// B*S=8192 queries (Q=512), K=32768 knowledge rows, H=1024.
// R7: 256x256 / BK=64 / 8-wave 8-phase counted-vmcnt schedule (all GEMMs).
// R8: one barrier per phase; pv slab stores + fused reduce_norm.
// R9: swapped-operand epilogues (contiguous out dim in acc reg index).
// R10: double-buffered fragment regs, reads hoisted one phase early.
// R11: clobber-free waitcnt asm + bare s_barrier (a "memory" clobber makes the
//      waitcnt pass drain vmcnt(0) at every barrier, silently turning the
//      counted pipeline into drain0). R=1024 chunks: P+VT+slab = 195MB < L3.
// R12: rule-#18 guard: __builtin_amdgcn_sched_barrier(0) pinning every bare
//      s_barrier and waitcnt asm (scheduling-only fence, emits nothing, does
//      NOT trigger waitcnt insertion) so the machine scheduler cannot move
//      ds_reads/MFMAs/stages across the sync points (m201 discipline).
// R13: resubmission of R12 -- R5/R6 failures were harness-level (container
//      acquisition / Trio nursery), not kernel: no divergent-barrier or
//      FIFO-imbalance hang path exists (re-audited; uniform barrier counts,
//      balanced vmcnt ledger, epilogue LDS reuse fenced + disjoint from the
//      last tile's outstanding reads).
// ---------------------------------------------------------------------------

typedef __bf16 bf16_t;
typedef __bf16 bf16x4 __attribute__((ext_vector_type(4)));
typedef __bf16 bf16x8 __attribute__((ext_vector_type(8)));
typedef _Float16 f16_t;
typedef _Float16 f16x4 __attribute__((ext_vector_type(4)));
typedef _Float16 f16x8 __attribute__((ext_vector_type(8)));
typedef float f32x4 __attribute__((ext_vector_type(4)));

#define KS   32768
#define HDIM 1024
#define QDIM 512
#define NQ   8192
#define SOFTMAX_C 90.0f

// ---------------------------------------------------------------------------
__device__ __forceinline__ void async16(const void* g, void* l) {
  __builtin_amdgcn_global_load_lds((const __attribute__((address_space(1))) void*)g,
                                   (__attribute__((address_space(3))) void*)l, 16, 0, 0);
}

// Bare workgroup barrier pinned by scheduling-only fences: no "memory"
// clobber (would insert vmcnt(0)), but nothing may be scheduler-moved across.
__device__ __forceinline__ void wg_barrier() {
  __builtin_amdgcn_sched_barrier(0);
  __builtin_amdgcn_s_barrier();
  __builtin_amdgcn_sched_barrier(0);
}

__device__ __forceinline__ void wait_vm6() {
  asm volatile("s_waitcnt vmcnt(6)");
  __builtin_amdgcn_sched_barrier(0);
}
__device__ __forceinline__ void wait_vm0() {
  asm volatile("s_waitcnt vmcnt(0)");
  __builtin_amdgcn_sched_barrier(0);
}

// ---------------------------------------------------------------------------
// 256x256 8-phase core. Half-tile = 256 rows x 32 k (16KB), 2 loads/thread.
// LDS per half: [256][32], 16B-piece swizzle c' = c ^ ((row>>1)&3), applied on
// the global source (LDS written linearly) and on the ds_read side.
// ---------------------------------------------------------------------------
template <typename T>
__device__ __forceinline__ void stage_half(const T* gbase, size_t ld, int gk,
                                           T* ldsbase, int wave, int lane) {
#pragma unroll
  for (int g = 0; g < 2; ++g) {
    const int slot = g * 512 + wave * 64 + lane;
    const int row = slot >> 2;
    const int cx = (slot & 3) ^ ((row >> 1) & 3);
    const T* src = gbase + (size_t)row * ld + (size_t)gk + cx * 8;
    async16((const void*)src, (void*)(ldsbase + g * 4096 + wave * 512));
  }
}

struct MF16 {
  typedef f16_t T; typedef f16x8 V8;
  static __device__ __forceinline__ f32x4 mm(V8 a, V8 b, f32x4 c) {
    return __builtin_amdgcn_mfma_f32_16x16x32_f16(a, b, c, 0, 0, 0);
  }
};
struct MBF16 {
  typedef bf16_t T; typedef bf16x8 V8;
  static __device__ __forceinline__ f32x4 mm(V8 a, V8 b, f32x4 c) {
    return __builtin_amdgcn_mfma_f32_16x16x32_bf16(a, b, c, 0, 0, 0);
  }
};

// sm: 65536 elems (128KB). buf b at b*32768: A-k0 @ +0, A-k1 @ +8192,
// B-k0 @ +16384, B-k1 @ +24576.
// Phase p: [stage_p ; (P4: counted vmcnt) ; barrier ; reads_{p+1} ; MFMA_p]
// vmcnt(6) once per K-tile: at P4 the 8 drained-oldest loads are exactly the
// four halves of tile t+1 (FIFO-verified incl. prologue).
// RAW: every read's consuming MFMA is one full phase later. WAR: stage write
// vs last LDS read of region separated by >=1 barrier + vmem latency.
template <class M>
__device__ __forceinline__ void gemm256_8p(
    const typename M::T* __restrict__ A, size_t lda,
    const typename M::T* __restrict__ B, size_t ldb,
    int kbeg, int ktiles, typename M::T* sm,
    f32x4 (&acc)[8][4], int wave, int lane) {
  typedef typename M::T T;
  typedef typename M::V8 V8;
  const int wm = wave & 1, wn = wave >> 1;
  const int qd = lane >> 4, ln = lane & 15;
  const int arow = wm * 128 + ln;
  const int brow = wn * 64 + ln;
  const int cxr = (qd ^ ((ln >> 1) & 3)) * 8;

  // prologue: T0{H0..H3}, T1{H0,H1,H2}; vmcnt(6) drains exactly T0 (8 loads)
  stage_half(B, ldb, kbeg +  0, sm + 16384, wave, lane);
  stage_half(B, ldb, kbeg + 32, sm + 24576, wave, lane);
  stage_half(A, lda, kbeg +  0, sm +     0, wave, lane);
  stage_half(A, lda, kbeg + 32, sm +  8192, wave, lane);
  stage_half(B, ldb, kbeg + 64, sm + 32768 + 16384, wave, lane);
  stage_half(B, ldb, kbeg + 96, sm + 32768 + 24576, wave, lane);
  stage_half(A, lda, kbeg + 64, sm + 32768, wave, lane);
  wait_vm6();
  wg_barrier();   // all waves' T0 stages drained -> T0-P1 reads safe below

  V8 arA[4], arB[4], brA[4], brB[4];
#pragma unroll
  for (int j = 0; j < 4; ++j) brA[j] = *(const V8*)&sm[16384 + (brow + j * 16) * 32 + cxr];
#pragma unroll
  for (int i = 0; i < 4; ++i) arA[i] = *(const V8*)&sm[(arow + i * 16) * 32 + cxr];

  for (int t = 0; t < ktiles; ++t) {
    const int b = t & 1;
    T* bufA = sm + b * 32768;
    T* bufB = bufA + 16384;
    T* obufA = sm + (b ^ 1) * 32768;
    T* obufB = obufA + 16384;
    const int kt = kbeg + t * 64;
    // ---- P1: stage A(t+1)k1; reads for P2 (k1 m0-3 + B k1); MFMA k0 m0-3
    if (t + 1 < ktiles) stage_half(A, lda, kt + 96, obufA + 8192, wave, lane);
    wg_barrier();
#pragma unroll
    for (int j = 0; j < 4; ++j) brB[j] = *(const V8*)&bufB[8192 + (brow + j * 16) * 32 + cxr];
#pragma unroll
    for (int i = 0; i < 4; ++i) arB[i] = *(const V8*)&bufA[8192 + (arow + i * 16) * 32 + cxr];
    __builtin_amdgcn_s_setprio(1);
#pragma unroll
    for (int i = 0; i < 4; ++i)
#pragma unroll
      for (int j = 0; j < 4; ++j) acc[i][j] = M::mm(arA[i], brA[j], acc[i][j]);
    __builtin_amdgcn_s_setprio(0);
    // ---- P2: stage B(t+2)k0; reads for P3 (k0 m4-7); MFMA k1 m0-3
    if (t + 2 < ktiles) stage_half(B, ldb, kt + 128, bufB, wave, lane);
    wg_barrier();
#pragma unroll
    for (int i = 0; i < 4; ++i) arA[i] = *(const V8*)&bufA[(arow + 64 + i * 16) * 32 + cxr];
    __builtin_amdgcn_s_setprio(1);
#pragma unroll
    for (int i = 0; i < 4; ++i)
#pragma unroll
      for (int j = 0; j < 4; ++j) acc[i][j] = M::mm(arB[i], brB[j], acc[i][j]);
    __builtin_amdgcn_s_setprio(0);
    // ---- P3: stage B(t+2)k1; reads for P4 (k1 m4-7); MFMA k0 m4-7 (brA reused)
    if (t + 2 < ktiles) stage_half(B, ldb, kt + 160, bufB + 8192, wave, lane);
    wg_barrier();
#pragma unroll
    for (int i = 0; i < 4; ++i) arB[i] = *(const V8*)&bufA[8192 + (arow + 64 + i * 16) * 32 + cxr];
    __builtin_amdgcn_s_setprio(1);
#pragma unroll
    for (int i = 0; i < 4; ++i)
#pragma unroll
      for (int j = 0; j < 4; ++j) acc[4 + i][j] = M::mm(arA[i], brA[j], acc[4 + i][j]);
    __builtin_amdgcn_s_setprio(0);
    // ---- P4: stage A(t+2)k0; counted vmcnt; reads for T(t+1)-P1; MFMA k1 m4-7
    if (t + 2 < ktiles) stage_half(A, lda, kt + 128, bufA, wave, lane);
    if (t + 2 < ktiles) { wait_vm6(); }
    else                { wait_vm0(); }
    wg_barrier();   // t+1 halves drained (all waves) -> t+1-P1 reads safe
    if (t + 1 < ktiles) {
#pragma unroll
      for (int j = 0; j < 4; ++j) brA[j] = *(const V8*)&obufB[(brow + j * 16) * 32 + cxr];
#pragma unroll
      for (int i = 0; i < 4; ++i) arA[i] = *(const V8*)&obufA[(arow + i * 16) * 32 + cxr];
    }
    __builtin_amdgcn_s_setprio(1);
#pragma unroll
    for (int i = 0; i < 4; ++i)
#pragma unroll
      for (int j = 0; j < 4; ++j) acc[4 + i][j] = M::mm(arB[i], brB[j], acc[4 + i][j]);
    __builtin_amdgcn_s_setprio(0);
  }
}

// ---------------------------------------------------------------------------
// prep kernels
// ---------------------------------------------------------------------------
__global__ __launch_bounds__(256) void prep_q(const float* __restrict__ q,
                                              f16_t* __restrict__ qf) {
  int g = blockIdx.x * 256 + threadIdx.x;
  float4 v = *(const float4*)(q + (size_t)g * 4);
  f16x4 h;
  h[0] = (f16_t)v.x; h[1] = (f16_t)v.y; h[2] = (f16_t)v.z; h[3] = (f16_t)v.w;
  *(f16x4*)(qf + (size_t)g * 4) = h;
}

__global__ __launch_bounds__(256) void prep_bank(const float* __restrict__ bank,
                                                 f16_t* __restrict__ bh,
                                                 bf16_t* __restrict__ bb) {
  size_t g = (size_t)blockIdx.x * 256 + threadIdx.x;
  float4 v = *(const float4*)(bank + g * 4);
  f16x4 h;
  h[0] = (f16_t)v.x; h[1] = (f16_t)v.y; h[2] = (f16_t)v.z; h[3] = (f16_t)v.w;
  *(f16x4*)(bh + g * 4) = h;
  bf16x4 b;
  b[0] = (bf16_t)v.x; b[1] = (bf16_t)v.y; b[2] = (bf16_t)v.z; b[3] = (bf16_t)v.w;
  *(bf16x4*)(bb + g * 4) = b;
}

__global__ __launch_bounds__(256) void prep_wk(const float* __restrict__ Wk,
                                               f16_t* __restrict__ WkTf) {
  int t = blockIdx.x * 256 + threadIdx.x;
  int n = t >> 10, k = t & 1023;
  WkTf[t] = (f16_t)Wk[(size_t)k * QDIM + n];
}

__global__ __launch_bounds__(256) void prep_wv(const float* __restrict__ Wv,
                                               bf16_t* __restrict__ WvT) {
  int t = blockIdx.x * 256 + threadIdx.x;
  int n = t >> 10, k = t & 1023;
  WvT[t] = (bf16_t)(Wv[(size_t)k * HDIM + n]);
}

// ---------------------------------------------------------------------------
// keys GEMM (fp16, 8-phase, swapped): C[keycol][bank] = WkTf x bh
// kf[bank][keycol]: per-thread 4 consecutive keycols -> 8B stores.
// ---------------------------------------------------------------------------
__global__ __launch_bounds__(512, 2) void keys_gemm_8p(
    const f16_t* __restrict__ bh, const f16_t* __restrict__ WkTf,
    const float* __restrict__ bk, f16_t* __restrict__ kf) {
  __shared__ alignas(16) f16_t sm[65536];
  const int tid = threadIdx.x, lane = tid & 63, wave = tid >> 6;
  const int mt = blockIdx.x & 1;        // keycol tile (A side)
  const int nt = blockIdx.x >> 1;       // bank tile (B side)
  f32x4 acc[8][4] = {};
  gemm256_8p<MF16>(WkTf + (size_t)(mt * 256) * HDIM, HDIM,
                   bh + (size_t)(nt * 256) * HDIM, HDIM, 0, HDIM / 64, sm, acc, wave, lane);
  const int wm = wave & 1, wn = wave >> 1;
  const int qd = lane >> 4, ln = lane & 15;
#pragma unroll
  for (int ii = 0; ii < 8; ++ii) {
    const int kcb = mt * 256 + wm * 128 + ii * 16 + qd * 4;
    const float4 b4 = *(const float4*)&bk[kcb];
#pragma unroll
    for (int j = 0; j < 4; ++j) {
      const int bank = nt * 256 + wn * 64 + j * 16 + ln;
      f16x4 o;
      o[0] = (f16_t)(acc[ii][j][0] + b4.x);
      o[1] = (f16_t)(acc[ii][j][1] + b4.y);
      o[2] = (f16_t)(acc[ii][j][2] + b4.z);
      o[3] = (f16_t)(acc[ii][j][3] + b4.w);
      *(f16x4*)&kf[(size_t)bank * QDIM + kcb] = o;
    }
  }
}

// ---------------------------------------------------------------------------
// values GEMM (bf16, 8-phase, swapped): C[k][h] = bank x WvT
// VT[h][k]: per-thread 4 consecutive k -> 8B stores.
// ---------------------------------------------------------------------------
__global__ __launch_bounds__(512, 2) void values_gemm_8p(
    const bf16_t* __restrict__ bb, const bf16_t* __restrict__ WvT,
    const float* __restrict__ bv, bf16_t* __restrict__ VT) {
  __shared__ alignas(16) bf16_t sm[65536];
  const int tid = threadIdx.x, lane = tid & 63, wave = tid >> 6;
  const int nt = blockIdx.x & 3;        // h tile (B side)
  const int mt = blockIdx.x >> 2;       // knowledge tile (A side)
  f32x4 acc[8][4] = {};
  gemm256_8p<MBF16>(bb + (size_t)(mt * 256) * HDIM, HDIM,
                    WvT + (size_t)(nt * 256) * HDIM, HDIM, 0, HDIM / 64, sm, acc, wave, lane);
  const int wm = wave & 1, wn = wave >> 1;
  const int qd = lane >> 4, ln = lane & 15;
#pragma unroll
  for (int j = 0; j < 4; ++j) {
    const int hh = nt * 256 + wn * 64 + j * 16 + ln;
    const float bvh = bv[hh];
#pragma unroll
    for (int ii = 0; ii < 8; ++ii) {
      const int kcb = mt * 256 + wm * 128 + ii * 16 + qd * 4;
      bf16x4 o;
      o[0] = (bf16_t)(acc[ii][j][0] + bvh);
      o[1] = (bf16_t)(acc[ii][j][1] + bvh);
      o[2] = (bf16_t)(acc[ii][j][2] + bvh);
      o[3] = (bf16_t)(acc[ii][j][3] + bvh);
      *(bf16x4*)&VT[(size_t)hh * KS + kcb] = o;
    }
  }
}

// ---------------------------------------------------------------------------
// fused score GEMM (fp16, K=512, 8-phase, swapped: C[kcol][qrow]) + softmax.
// P[qrow][kcol]: per-thread 4 consecutive kcols -> 8B stores; row-reduce is
// 2 shuffles (xor 16,32) + 4 LDS atomics. lpart width = KS/256 = 128.
// ---------------------------------------------------------------------------
__global__ __launch_bounds__(512, 2) void score_fused_8p(
    const f16_t* __restrict__ qf, const f16_t* __restrict__ kf,
    bf16_t* __restrict__ P, float* __restrict__ lpart, int row0, int mtiles) {
  __shared__ alignas(16) f16_t sm[65536];
  const int tid = threadIdx.x, lane = tid & 63, wave = tid >> 6;
  const int bid = blockIdx.x;
  const int logical = (bid & 7) * ((int)gridDim.x >> 3) + (bid >> 3);
  const int mt_ = logical % mtiles;   // q tile (B side now)
  const int nt_ = logical / mtiles;   // k tile (A side now)
  const int q0 = mt_ * 256, k0 = nt_ * 256;
  f32x4 acc[8][4] = {};
  gemm256_8p<MF16>(kf + (size_t)k0 * QDIM, QDIM,
                   qf + (size_t)(row0 + q0) * QDIM, QDIM, 0, QDIM / 64, sm, acc, wave, lane);

  const int wm = wave & 1, wn = wave >> 1;
  const int qd = lane >> 4, ln = lane & 15;
  float* ls = (float*)sm;
  if (tid < 256) ls[tid] = 0.f;
  __syncthreads();
  float rsum[4] = {0.f, 0.f, 0.f, 0.f};
#pragma unroll
  for (int ii = 0; ii < 8; ++ii) {
    const int kcb = k0 + wm * 128 + ii * 16 + qd * 4;
#pragma unroll
    for (int j = 0; j < 4; ++j) {
      const int qr = q0 + wn * 64 + j * 16 + ln;
      bf16x4 pb;
      float s4 = 0.f;
#pragma unroll
      for (int r = 0; r < 4; ++r) {
        float e = __expf(acc[ii][j][r] - SOFTMAX_C);
        pb[r] = (bf16_t)e;
        s4 += (float)pb[r];
      }
      *(bf16x4*)&P[(size_t)qr * KS + kcb] = pb;
      rsum[j] += s4;
    }
  }
#pragma unroll
  for (int j = 0; j < 4; ++j) {
    float s = rsum[j];
    s += __shfl_xor(s, 16);
    s += __shfl_xor(s, 32);
    if (qd == 0) atomicAdd(&ls[wn * 64 + j * 16 + ln], s);
  }
  __syncthreads();
  if (tid < 256)
    lpart[(size_t)(row0 + q0 + tid) * (KS / 256) + nt_] = ls[tid];
}

// ---------------------------------------------------------------------------
// PV GEMM (bf16, 8-phase, swapped: C[h][qrow]): slab[z][qrow][h] over k-span.
// Per-thread 4 consecutive h -> 16B f32x4 stores.
// ---------------------------------------------------------------------------
__global__ __launch_bounds__(512, 2) void pv_gemm_8p(
    const bf16_t* __restrict__ P, const bf16_t* __restrict__ VT,
    float* __restrict__ slab, int mtiles, int zsplit) {
  __shared__ alignas(16) bf16_t sm[65536];
  const int tid = threadIdx.x, lane = tid & 63, wave = tid >> 6;
  const int bid = blockIdx.x;
  const int z = bid % zsplit;
  const int idx = bid / zsplit;
  const int mt_ = idx % mtiles;       // q tile (B side now)
  const int nt_ = idx / mtiles;       // h tile (A side now)
  const int q0 = mt_ * 256;
  const int h0 = nt_ * 256;
  const int kspan = KS / zsplit;
  const int kbeg = z * kspan;
  f32x4 acc[8][4] = {};
  gemm256_8p<MBF16>(VT + (size_t)h0 * KS, KS,
                    P + (size_t)q0 * KS, KS, kbeg, kspan / 64, sm, acc, wave, lane);

  const int wm = wave & 1, wn = wave >> 1;
  const int qd = lane >> 4, ln = lane & 15;
  float* slabz = slab + (size_t)z * (size_t)(mtiles * 256) * HDIM;
#pragma unroll
  for (int j = 0; j < 4; ++j) {
    const int qr = q0 + wn * 64 + j * 16 + ln;
#pragma unroll
    for (int ii = 0; ii < 8; ++ii) {
      const int hcb = h0 + wm * 128 + ii * 16 + qd * 4;
      *(f32x4*)&slabz[(size_t)qr * HDIM + hcb] = acc[ii][j];
    }
  }
}

// ---------------------------------------------------------------------------
// fused reduce over z-slabs + softmax normalization. One block per chunk row.
// ---------------------------------------------------------------------------
__global__ __launch_bounds__(256) void reduce_norm(const float* __restrict__ slab,
                                                   const float* __restrict__ lpart,
                                                   float* __restrict__ Out,
                                                   int row0, int R, int zsplit) {
  const int row = blockIdx.x;
  float s = (threadIdx.x < 128) ? lpart[(size_t)(row0 + row) * (KS / 256) + threadIdx.x] : 0.f;
#pragma unroll
  for (int off = 32; off; off >>= 1) s += __shfl_xor(s, off);
  __shared__ float red[4];
  if ((threadIdx.x & 63) == 0) red[threadIdx.x >> 6] = s;
  __syncthreads();
  const float linv = 1.0f / (red[0] + red[1] + red[2] + red[3]);
  const float* p = slab + (size_t)row * HDIM + threadIdx.x * 4;
  float4 a = make_float4(0.f, 0.f, 0.f, 0.f);
  for (int zz = 0; zz < zsplit; ++zz) {
    float4 v = *(const float4*)(p + (size_t)zz * R * HDIM);
    a.x += v.x; a.y += v.y; a.z += v.z; a.w += v.w;
  }
  a.x *= linv; a.y *= linv; a.z *= linv; a.w *= linv;
  *(float4*)(Out + (size_t)(row0 + row) * HDIM + threadIdx.x * 4) = a;
}

// ---------------------------------------------------------------------------
extern "C" void kernel_launch(void* const* d_in, const int* in_sizes, int n_in,
                              void* d_out, int out_size, void* d_ws, size_t ws_size,
                              hipStream_t stream) {
  const float* q    = (const float*)d_in[0];
  const float* bank = (const float*)d_in[1];
  const float* Wk   = (const float*)d_in[2];
  const float* bk   = (const float*)d_in[3];
  const float* Wv   = (const float*)d_in[4];
  const float* bv   = (const float*)d_in[5];
  float* out = (float*)d_out;
  char* ws = (char*)d_ws;

  size_t off = 0;
  f16_t*  qf    = (f16_t*)(ws + off);  off += (size_t)NQ * QDIM * 2;
  f16_t*  kf    = (f16_t*)(ws + off);  off += (size_t)KS * QDIM * 2;
  bf16_t* VT    = (bf16_t*)(ws + off); off += (size_t)HDIM * KS * 2;
  f16_t*  bkf16 = (f16_t*)(ws + off);  off += (size_t)KS * HDIM * 2;   // bank f16; dead after keys -> slab
  bf16_t* bkbf  = (bf16_t*)(ws + off); off += (size_t)KS * HDIM * 2;   // bank bf16
  f16_t*  wkf   = (f16_t*)(ws + off);  off += (size_t)QDIM * HDIM * 2;
  bf16_t* wvt   = (bf16_t*)(ws + off); off += (size_t)HDIM * HDIM * 2;
  float*  lpart = (float*)(ws + off);  off += (size_t)NQ * 256 * 4;

  // R=1024: P chunk (64MB) + VT (64MB) + slab (64MB) = 195MB < 256MB L3
  int R = 1024;
  while (R > 256 && off + (size_t)R * KS * 2 > ws_size) R >>= 1;
  bf16_t* P = (bf16_t*)(ws + off);
  const int Rm = R / 256;

  // pv k-split: zsplit*R = 16384 => slab = zsplit*R*HDIM*4B = 64MB = |bkf16|
  int zsplit = 16384 / R;
  if (zsplit < 8) zsplit = 8;
  if (zsplit > 64) zsplit = 64;
  float* slab = (float*)bkf16;       // aliased; keys_gemm finished before pv

  prep_q   <<<NQ * QDIM / 4 / 256, 256, 0, stream>>>(q, qf);
  prep_bank<<<KS * HDIM / 4 / 256, 256, 0, stream>>>(bank, bkf16, bkbf);
  prep_wk  <<<QDIM * HDIM / 256, 256, 0, stream>>>(Wk, wkf);
  prep_wv  <<<HDIM * HDIM / 256, 256, 0, stream>>>(Wv, wvt);
  keys_gemm_8p  <<<(QDIM / 256) * (KS / 256), 512, 0, stream>>>(bkf16, wkf, bk, kf);
  values_gemm_8p<<<(HDIM / 256) * (KS / 256), 512, 0, stream>>>(bkbf, wvt, bv, VT);

  for (int row0 = 0; row0 < NQ; row0 += R) {
    score_fused_8p<<<(KS / 256) * Rm, 512, 0, stream>>>(qf, kf, P, lpart, row0, Rm);
    pv_gemm_8p    <<<zsplit * Rm * (HDIM / 256), 512, 0, stream>>>(P, VT, slab, Rm, zsplit);
    reduce_norm   <<<R, 256, 0, stream>>>(slab, lpart, out, row0, R, zsplit);
  }
}